// Round 5
// baseline (276.904 us; speedup 1.0000x reference)
//
#include <hip/hip_runtime.h>
#include <hip/hip_fp16.h>

// PathWAEOld — R5: gather is per-CU outstanding-miss (MSHR) bound:
// R3(16 waves/CU)=134us, R4(25 waves/CU)=146us, same 388MB FETCH, same BW
// => shared-resource saturation, lever is FEWER CACHE LINES.
// Convert E_td|E_wae -> interleaved fp16 table (400B/row, halves line count),
// packed-half accumulate, fuse final head via last-block ticket.
// Fallback to verified fp32 path if ws too small.

#define NPATH 16384
#define PLEN  50
#define RANDD 100
#define VDIMD 100
#define WAED  50
#define NCLS  4
#define HD    150
#define NBLK  1024   // 4096 waves, 4 paths/wave
#define NCVT  (100000 * 50)   // convert threads: 4 floats each

// order-preserving float<->uint for atomicMax on floats
__device__ __forceinline__ unsigned f2o(float f) {
    unsigned u = __float_as_uint(f);
    return (u & 0x80000000u) ? ~u : (u | 0x80000000u);
}
__device__ __forceinline__ float o2f(unsigned u) {
    return (u & 0x80000000u) ? __uint_as_float(u & 0x7FFFFFFFu)
                             : __uint_as_float(~u);
}

// ---- convert: E_td[100k][100] f32 + E_wae[100k][100] f32 ->
//      T[100k][200] half, row = [td | wae], 400B, contiguous ----
__global__ void __launch_bounds__(256)
convert_tables(const float* __restrict__ E_td,
               const float* __restrict__ E_wae,
               __half* __restrict__ T)
{
    int i = blockIdx.x * 256 + threadIdx.x;
    if (i >= NCVT) return;
    int tok = i / 50;
    int d   = (i - tok * 50) * 4;          // 0..196, step 4
    const float* src = (d < 100) ? (E_td + tok * 100 + d)
                                 : (E_wae + tok * 100 + (d - 100));
    float4 v = *(const float4*)src;
    __half2 h0 = __float22half2_rn(make_float2(v.x, v.y));
    __half2 h1 = __float22half2_rn(make_float2(v.z, v.w));
    __half2* dst = (__half2*)(T + (size_t)tok * 200 + d);
    dst[0] = h0; dst[1] = h1;
}

// ---- main (fp16 combined table), head fused via last-block ticket ----
__global__ void __launch_bounds__(256, 5)
pathwae_main16(const int* __restrict__ x,
               const __half* __restrict__ T,
               const float* __restrict__ W_enc,
               const float* __restrict__ b_enc,
               const int* __restrict__ y,
               const float* __restrict__ w_out,
               const float* __restrict__ b_out,
               unsigned int* __restrict__ gmax,
               unsigned int* __restrict__ done,
               float* __restrict__ out)
{
    __shared__ float sh_W[VDIMD * WAED];      // 20 KB
    __shared__ float sh_comb[4][2][200];      // 6.4 KB per-wave A/B partials
    __shared__ float sh_bow[4][VDIMD];        // 1.6 KB
    __shared__ float sh_wmax[4][HD];          // 2.4 KB
    __shared__ int   sh_last;

    const int tid  = threadIdx.x;
    const int lane = tid & 63;
    const int warp = tid >> 6;

    for (int i = tid; i < VDIMD * WAED; i += 256) sh_W[i] = W_enc[i];
    __syncthreads();

    const int gwave = blockIdx.x * 4 + warp;
    const int nwave = NBLK * 4;

    const bool act = (lane < 50);
    const int  g   = (lane < 25) ? 0 : 1;     // token-A group / token-B group
    const int  c   = lane - 25 * g;           // 16B chunk 0..24 within row

    float m0 = -3.4e38f, m1 = -3.4e38f, maxwae = -3.4e38f;
    const float benc = act ? b_enc[lane] : 0.0f;
    const __half2 hz = __float2half2_rn(0.0f);

    for (int p = gwave; p < NPATH; p += nwave) {
        int mytok = act ? x[p * PLEN + lane] : 0;
        __half2 h0 = hz, h1 = hz, h2 = hz, h3 = hz;
        #pragma unroll
        for (int l = 0; l < 25; ++l) {
            int tokA = __shfl(mytok, 2 * l);
            int tokB = __shfl(mytok, 2 * l + 1);
            if (act) {
                int tok = g ? tokB : tokA;
                // 16B = 8 halfs; byte off = tok*400 + 16c (16B aligned)
                float4 r = *(const float4*)(T + (size_t)tok * 200 + (c << 3));
                const __half2* hp = (const __half2*)&r;
                h0 = __hadd2(h0, hp[0]); h1 = __hadd2(h1, hp[1]);
                h2 = __hadd2(h2, hp[2]); h3 = __hadd2(h3, hp[3]);
            }
        }
        if (act) {
            float* dstp = &sh_comb[warp][g][c << 3];
            dstp[0] = __low2float(h0);  dstp[1] = __high2float(h0);
            dstp[2] = __low2float(h1);  dstp[3] = __high2float(h1);
            dstp[4] = __low2float(h2);  dstp[5] = __high2float(h2);
            dstp[6] = __low2float(h3);  dstp[7] = __high2float(h3);
        }
        // same-wave LDS write->read, program order (R3-verified pattern)
        if (act) {
            const int d0 = 2 * lane;              // td dims 0..99
            float v0 = sh_comb[warp][0][d0]     + sh_comb[warp][1][d0];
            float v1 = sh_comb[warp][0][d0 + 1] + sh_comb[warp][1][d0 + 1];
            v0 = v0 > 0.f ? v0 : 0.01f * v0;
            v1 = v1 > 0.f ? v1 : 0.01f * v1;
            m0 = fmaxf(m0, v0); m1 = fmaxf(m1, v1);
            float b0 = sh_comb[warp][0][100 + d0]     + sh_comb[warp][1][100 + d0];
            float b1 = sh_comb[warp][0][100 + d0 + 1] + sh_comb[warp][1][100 + d0 + 1];
            sh_bow[warp][d0] = b0; sh_bow[warp][d0 + 1] = b1;
            float w = benc;
            #pragma unroll 10
            for (int i = 0; i < VDIMD; ++i)
                w = fmaf(sh_bow[warp][i], sh_W[i * WAED + lane], w);
            w = fmaxf(w, 0.0f);                   // relu (leaky of >=0 = id)
            maxwae = fmaxf(maxwae, w);
        }
    }

    if (act) {
        sh_wmax[warp][2 * lane]     = m0;
        sh_wmax[warp][2 * lane + 1] = m1;
        sh_wmax[warp][RANDD + lane] = maxwae;
    }
    __syncthreads();
    if (tid < HD) {
        float m = fmaxf(fmaxf(sh_wmax[0][tid], sh_wmax[1][tid]),
                        fmaxf(sh_wmax[2][tid], sh_wmax[3][tid]));
        atomicMax(&gmax[tid], f2o(m));
    }
    __threadfence();
    if (tid == 0) sh_last = (atomicAdd(done, 1u) == (unsigned)(gridDim.x - 1));
    __syncthreads();
    if (!sh_last) return;

    // ---- final head, executed by the last block only ----
    __shared__ float pm[HD];
    __shared__ float lg[NCLS];
    if (tid < HD) pm[tid] = o2f(atomicMax(&gmax[tid], 0u));  // coherent read
    __syncthreads();
    if (tid < NCLS) {
        float s = b_out[tid];
        for (int d = 0; d < HD; ++d) s = fmaf(w_out[tid * HD + d], pm[d], s);
        lg[tid] = s;
    }
    __syncthreads();
    if (tid == 0) {
        int label = 0, best = y[0];
        for (int cc = 1; cc < NCLS; ++cc)
            if (y[cc] > best) { best = y[cc]; label = cc; }
        float m = lg[0];
        for (int cc = 1; cc < NCLS; ++cc) m = fmaxf(m, lg[cc]);
        float e[NCLS], s = 0.f;
        for (int cc = 0; cc < NCLS; ++cc) { e[cc] = expf(lg[cc] - m); s += e[cc]; }
        float prob[NCLS];
        for (int cc = 0; cc < NCLS; ++cc) prob[cc] = e[cc] / s;
        float m2 = prob[0];
        for (int cc = 1; cc < NCLS; ++cc) m2 = fmaxf(m2, prob[cc]);
        float s2 = 0.f;
        for (int cc = 0; cc < NCLS; ++cc) s2 += expf(prob[cc] - m2);
        float lse = m2 + logf(s2);
        for (int cc = 0; cc < NCLS; ++cc) out[cc] = prob[cc];
        out[NCLS] = -(prob[label] - lse);
    }
}

// ---- fp32 fallback (verified bit-exact in R3) ----
__global__ void __launch_bounds__(256)
pathwae_main_f32(const int* __restrict__ x,
                 const float* __restrict__ E_td,
                 const float* __restrict__ E_wae,
                 const float* __restrict__ W_enc,
                 const float* __restrict__ b_enc,
                 unsigned int* __restrict__ gmax)
{
    __shared__ float sh_W[VDIMD * WAED];
    __shared__ float sh_bow[4][VDIMD];
    __shared__ float sh_wmax[4][HD];
    const int tid = threadIdx.x, lane = tid & 63, warp = tid >> 6;
    for (int i = tid; i < VDIMD * WAED; i += 256) sh_W[i] = W_enc[i];
    __syncthreads();
    const int gwave = blockIdx.x * 4 + warp, nwave = NBLK * 4;
    const bool is_td = (lane < 25), active = (lane < 50);
    const int chunk = is_td ? lane : (lane - 25);
    const float* tab = is_td ? E_td : E_wae;
    float4 maxtd = make_float4(-3.4e38f, -3.4e38f, -3.4e38f, -3.4e38f);
    float maxwae = -3.4e38f;
    const float benc = (lane < WAED) ? b_enc[lane] : 0.0f;
    for (int p = gwave; p < NPATH; p += nwave) {
        int mytok = (lane < PLEN) ? x[p * PLEN + lane] : 0;
        float ax = 0.f, ay = 0.f, az = 0.f, aw = 0.f;
        #pragma unroll 10
        for (int l = 0; l < PLEN; ++l) {
            int tok = __shfl(mytok, l);
            if (active) {
                float4 v = *(const float4*)(tab + tok * 100 + chunk * 4);
                ax += v.x; ay += v.y; az += v.z; aw += v.w;
            }
        }
        if (active && !is_td) {
            float* dst = &sh_bow[warp][chunk * 4];
            dst[0] = ax; dst[1] = ay; dst[2] = az; dst[3] = aw;
        }
        if (lane < WAED) {
            float w = benc;
            #pragma unroll 10
            for (int i = 0; i < VDIMD; ++i)
                w = fmaf(sh_bow[warp][i], sh_W[i * WAED + lane], w);
            w = fmaxf(w, 0.0f);
            maxwae = fmaxf(maxwae, w);
        }
        if (is_td) {
            maxtd.x = fmaxf(maxtd.x, ax > 0.f ? ax : 0.01f * ax);
            maxtd.y = fmaxf(maxtd.y, ay > 0.f ? ay : 0.01f * ay);
            maxtd.z = fmaxf(maxtd.z, az > 0.f ? az : 0.01f * az);
            maxtd.w = fmaxf(maxtd.w, aw > 0.f ? aw : 0.01f * aw);
        }
    }
    if (is_td) {
        sh_wmax[warp][chunk * 4 + 0] = maxtd.x;
        sh_wmax[warp][chunk * 4 + 1] = maxtd.y;
        sh_wmax[warp][chunk * 4 + 2] = maxtd.z;
        sh_wmax[warp][chunk * 4 + 3] = maxtd.w;
    }
    if (lane < WAED) sh_wmax[warp][RANDD + lane] = maxwae;
    __syncthreads();
    if (tid < HD) {
        float m = fmaxf(fmaxf(sh_wmax[0][tid], sh_wmax[1][tid]),
                        fmaxf(sh_wmax[2][tid], sh_wmax[3][tid]));
        atomicMax(&gmax[tid], f2o(m));
    }
}

__global__ void __launch_bounds__(256)
pathwae_final(const unsigned int* __restrict__ gmax,
              const int* __restrict__ y,
              const float* __restrict__ w_out,
              const float* __restrict__ b_out,
              float* __restrict__ out)
{
    __shared__ float pm[HD];
    __shared__ float lg[NCLS];
    const int tid = threadIdx.x;
    if (tid < HD) pm[tid] = o2f(gmax[tid]);
    __syncthreads();
    if (tid < NCLS) {
        float s = b_out[tid];
        for (int d = 0; d < HD; ++d) s = fmaf(w_out[tid * HD + d], pm[d], s);
        lg[tid] = s;
    }
    __syncthreads();
    if (tid == 0) {
        int label = 0, best = y[0];
        for (int c = 1; c < NCLS; ++c)
            if (y[c] > best) { best = y[c]; label = c; }
        float m = lg[0];
        for (int c = 1; c < NCLS; ++c) m = fmaxf(m, lg[c]);
        float e[NCLS], s = 0.f;
        for (int c = 0; c < NCLS; ++c) { e[c] = expf(lg[c] - m); s += e[c]; }
        float prob[NCLS];
        for (int c = 0; c < NCLS; ++c) prob[c] = e[c] / s;
        float m2 = prob[0];
        for (int c = 1; c < NCLS; ++c) m2 = fmaxf(m2, prob[c]);
        float s2 = 0.f;
        for (int c = 0; c < NCLS; ++c) s2 += expf(prob[c] - m2);
        float lse = m2 + logf(s2);
        for (int c = 0; c < NCLS; ++c) out[c] = prob[c];
        out[NCLS] = -(prob[label] - lse);
    }
}

extern "C" void kernel_launch(void* const* d_in, const int* in_sizes, int n_in,
                              void* d_out, int out_size, void* d_ws, size_t ws_size,
                              hipStream_t stream) {
    const int* x       = (const int*)d_in[0];
    const int* y       = (const int*)d_in[1];
    const float* E_td  = (const float*)d_in[2];
    const float* E_wae = (const float*)d_in[3];
    const float* W_enc = (const float*)d_in[4];
    const float* b_enc = (const float*)d_in[5];
    const float* w_out = (const float*)d_in[6];
    const float* b_out = (const float*)d_in[7];
    float* out         = (float*)d_out;

    unsigned int* gmax = (unsigned int*)d_ws;              // 150 u32
    unsigned int* done = gmax + HD;                        // 1 u32
    __half* T = (__half*)((char*)d_ws + 1024);             // 40 MB fp16 table
    const size_t need = 1024 + (size_t)100000 * 200 * sizeof(__half);

    hipMemsetAsync(d_ws, 0, 1024, stream);
    if (ws_size >= need) {
        convert_tables<<<(NCVT + 255) / 256, 256, 0, stream>>>(E_td, E_wae, T);
        pathwae_main16<<<NBLK, 256, 0, stream>>>(x, T, W_enc, b_enc,
                                                 y, w_out, b_out,
                                                 gmax, done, out);
    } else {
        pathwae_main_f32<<<NBLK, 256, 0, stream>>>(x, E_td, E_wae, W_enc,
                                                   b_enc, gmax);
        pathwae_final<<<1, 256, 0, stream>>>(gmax, y, w_out, b_out, out);
    }
}